// Round 1
// baseline (132.557 us; speedup 1.0000x reference)
//
#include <hip/hip_runtime.h>
#include <math.h>

#define NR 6   // Fourier terms r=1..NR; trunc error ~I_{NR+1}(1)/I_0(1) ~ 1.3e-6

typedef float v2f __attribute__((ext_vector_type(2)));

__device__ __forceinline__ v2f vfma2(v2f a, v2f b, v2f c) {
#if defined(__has_builtin)
#if __has_builtin(__builtin_elementwise_fma)
    return __builtin_elementwise_fma(a, b, c);
#else
    v2f r; r.x = fmaf(a.x, b.x, c.x); r.y = fmaf(a.y, b.y, c.y); return r;
#endif
#else
    v2f r; r.x = fmaf(a.x, b.x, c.x); r.y = fmaf(a.y, b.y, c.y); return r;
#endif
}

// J[r] = (r==0 ? 1 : 2) * I_r(t), modified Bessel, series (divisors fold to
// compile-time reciprocal multiplies after full unroll).
__device__ __forceinline__ void bessel_J(float t, float* J) {
    float h = 0.5f * t, q = h * h;
    float hp = 1.f, rf = 1.f;
#pragma unroll
    for (int r = 0; r <= NR; ++r) {
        if (r > 0) { hp *= h; rf *= (1.f / r); }
        float term = hp * rf, sum = term;
#pragma unroll
        for (int k = 1; k <= 12; ++k) {
            term *= q * (1.f / (k * (r + k)));
            sum += term;
        }
        J[r] = (r ? 2.f : 1.f) * sum;
    }
}

// Channel-attention collapsed map (exact): y4[2p+d] = A*y3[2p]+B*y3[2p+1]+C.
__device__ __forceinline__ void ca_coeffs(int p, int d,
        float s00, float s01, float s11, float m0, float m1,
        const float* __restrict__ wqkv, const float* __restrict__ bqkv,
        const float* __restrict__ t,    const float* __restrict__ wf,
        const float* __restrict__ bf,   float& A, float& B, float& C) {
    const float N = 1024.f;
    int c0 = 2 * p, c1 = 2 * p + 1;
    int c  = 2 * p + d;
    float Aa = 0.f, Bb = 0.f, Cc = 0.f;
#pragma unroll
    for (int e = 0; e < 2; ++e) {
        float wq0 = wqkv[c0 * 6 + e],     wq1 = wqkv[c1 * 6 + e];
        float bq0 = bqkv[c0 * 6 + e],     bq1 = bqkv[c1 * 6 + e];
        float wk0 = wqkv[c0 * 6 + 2 + e], wk1 = wqkv[c1 * 6 + 2 + e];
        float bk0 = bqkv[c0 * 6 + 2 + e], bk1 = bqkv[c1 * 6 + 2 + e];
        float wv0 = wqkv[c0 * 6 + 4 + e], wv1 = wqkv[c1 * 6 + 4 + e];
        float bv0 = bqkv[c0 * 6 + 4 + e], bv1 = bqkv[c1 * 6 + 4 + e];
        float te  = t[e * 32 + p];
        float sqq = (d == 0) ? (wq0 * wq0 * s00 + 2.f * wq0 * bq0 * m0 + N * bq0 * bq0)
                             : (wq1 * wq1 * s11 + 2.f * wq1 * bq1 * m1 + N * bq1 * bq1);
        float kk0 = wk0 * wk0 * s00 + 2.f * wk0 * bk0 * m0 + N * bk0 * bk0;
        float kk1 = wk1 * wk1 * s11 + 2.f * wk1 * bk1 * m1 + N * bk1 * bk1;
        float inq  = 1.f / fmaxf(sqrtf(fmaxf(sqq, 0.f)), 1e-12f);
        float ink0 = 1.f / fmaxf(sqrtf(fmaxf(kk0, 0.f)), 1e-12f);
        float ink1 = 1.f / fmaxf(sqrtf(fmaxf(kk1, 0.f)), 1e-12f);
        float qk0 = (d == 0) ? (wq0 * wk0 * s00 + wq0 * bk0 * m0 + bq0 * wk0 * m0 + N * bq0 * bk0)
                             : (wq1 * wk0 * s01 + wq1 * bk0 * m1 + bq1 * wk0 * m0 + N * bq1 * bk0);
        float qk1 = (d == 0) ? (wq0 * wk1 * s01 + wq0 * bk1 * m0 + bq0 * wk1 * m1 + N * bq0 * bk1)
                             : (wq1 * wk1 * s11 + wq1 * bk1 * m1 + bq1 * wk1 * m1 + N * bq1 * bk1);
        float L0 = qk0 * inq * ink0 * te, L1 = qk1 * inq * ink1 * te;
        float mx = fmaxf(L0, L1);
        float e0 = expf(L0 - mx), e1 = expf(L1 - mx);
        float iv = 1.f / (e0 + e1);
        float p0 = e0 * iv, p1 = e1 * iv;
        float f = wf[c * 2 + e];
        Aa += f * p0 * wv0;
        Bb += f * p1 * wv1;
        Cc += f * (p0 * bv0 + p1 * bv1);
    }
    A = Aa; B = Bb; C = Cc + bf[c];
}

// ---------------------------------------------------------------------------
// LDS: union of the three phase layouts (max = front, 34 KB -> worst-case
// packing still fits 4 blocks/CU, so all 256 blocks are always co-resident
// and the grid barrier cannot deadlock).
// ---------------------------------------------------------------------------
struct SmemF { float lxs[64 * 128]; float lwt[8][64]; };
struct SmemA { float ly[4][1024]; float redg[10][4]; float redm[4][39]; float momf[2][39]; };
struct SmemC { float lx[32 * 32]; float lw[64 * 32]; };
union SmemU { SmemF f; SmemA a; SmemC c; };

// Device-scope sense-free grid barrier: each of the two counters is used
// exactly once per launch and zeroed by a hipMemsetAsync node before the
// kernel node (workspace is re-poisoned by the harness each iteration, so
// state cannot persist anyway). Agent-scope acq_rel gives cross-XCD
// visibility of y3/y8 (per-XCD L2s are not coherent).
__device__ __forceinline__ void grid_bar(unsigned* cnt, unsigned target) {
    __syncthreads();
    if (threadIdx.x == 0) {
        __hip_atomic_fetch_add(cnt, 1u, __ATOMIC_ACQ_REL, __HIP_MEMORY_SCOPE_AGENT);
        while (__hip_atomic_load(cnt, __ATOMIC_ACQUIRE, __HIP_MEMORY_SCOPE_AGENT) < target)
            __builtin_amdgcn_s_sleep(1);
    }
    __syncthreads();
}

// ---------------------------------------------------------------------------
// Single fused kernel: phase F (1x1 conv + dw 2x2/s2 + permute) ->
// grid barrier -> phase A (channel attn collapsed + spatial attn via
// Fourier/Bessel moments + fuse + un1 + shuffle) -> grid barrier ->
// phase C (un2 1x1 conv, re-tiled to 256 blocks x 32 px x 64 outputs).
// Grid: 256 blocks x 256 threads.
// ---------------------------------------------------------------------------
__global__ __launch_bounds__(256) void k_fused(
        const float* __restrict__ x,
        const float* __restrict__ w1x1, const float* __restrict__ b1x1,
        const float* __restrict__ wdw,  const float* __restrict__ bdw,
        const float* __restrict__ ca_wqkv, const float* __restrict__ ca_bqkv,
        const float* __restrict__ ca_t,    const float* __restrict__ ca_wf,
        const float* __restrict__ ca_bf,
        const float* __restrict__ wqkv, const float* __restrict__ bqkv,
        const float* __restrict__ t,    const float* __restrict__ wf,
        const float* __restrict__ bfuse, const float* __restrict__ w1,
        const float* __restrict__ b1,
        const float* __restrict__ w2,   const float* __restrict__ b2,
        float* __restrict__ y3, float* __restrict__ y8,
        float* __restrict__ out, unsigned* __restrict__ bar) {
    __shared__ __align__(16) SmemU sm;
    int tid = threadIdx.x;
    int bid = blockIdx.x;

    // ================= phase F: front (proven k_front body) =================
    {
        int q   = bid & 3;
        int i32 = (bid >> 2) & 31;
        int b   = bid >> 7;
        const float4* x4 = (const float4*)x;
#pragma unroll
        for (int i = 0; i < 8; ++i) {
            int f4 = tid + i * 256;
            int c  = f4 >> 5, cw = f4 & 31;
            ((float4*)sm.f.lxs)[f4] = x4[(b * 64 + c) * 1024 + i32 * 32 + cw];
        }
        for (int idx = tid; idx < 512; idx += 256) {
            int gi = idx >> 6, c = idx & 63;
            int g = 4 * q + (gi & 3) + ((gi & 4) << 2);
            sm.f.lwt[gi][c] = w1x1[g * 64 + c];
        }
        __syncthreads();

        int gidx = tid >> 5, col = tid & 31;
        int g = 4 * q + (gidx & 3) + ((gidx & 4) << 2);
        v2f acc0 = {0.f, 0.f}, acc1 = {0.f, 0.f};
        const v2f* lx2 = (const v2f*)sm.f.lxs;
#pragma unroll 4
        for (int c = 0; c < 64; ++c) {
            float wv = sm.f.lwt[gidx][c];
            v2f wv2 = {wv, wv};
            acc0 = vfma2(wv2, lx2[c * 64 + col], acc0);
            acc1 = vfma2(wv2, lx2[c * 64 + 32 + col], acc1);
        }
        float bs = b1x1[g];
        float a00 = acc0.x + bs, a01 = acc0.y + bs;
        float a10 = acc1.x + bs, a11 = acc1.y + bs;
#pragma unroll
        for (int s = 0; s < 2; ++s) {
            int oc = 2 * g + s;
            int k  = 2 * (oc & 31) + (oc >> 5);   // permuted y3 channel
            float4 wd = ((const float4*)wdw)[oc];
            float v = bdw[oc];
            v = fmaf(wd.x, a00, v); v = fmaf(wd.y, a01, v);
            v = fmaf(wd.z, a10, v); v = fmaf(wd.w, a11, v);
            y3[(b * 64 + k) * 1024 + i32 * 32 + col] = v;
        }
    }
    grid_bar(bar + 0, 256);

    // ================= phase A: attention (proven k_attn body) ==============
    {
        int chunk = bid & 3;
        int j = (bid >> 2) & 31;
        int b = bid >> 7;
        int jp = j & 15;
        int dsel = j >> 4;
        int c0 = 2 * j, c1 = 2 * j + 1;

        // ---- stage 4 y3 channels + Gram stats for both ca pairs ----
        const float* base = y3 + (b * 64 + 4 * jp) * 1024;
        float sA00 = 0, sA01 = 0, sA11 = 0, mA0 = 0, mA1 = 0;
        float sB00 = 0, sB01 = 0, sB11 = 0, mB0 = 0, mB1 = 0;
#pragma unroll
        for (int r = 0; r < 4; ++r) {
            int n = tid + r * 256;
            float a0 = base[n], a1 = base[1024 + n];
            float a2 = base[2048 + n], a3 = base[3072 + n];
            sm.a.ly[0][n] = a0; sm.a.ly[1][n] = a1;
            sm.a.ly[2][n] = a2; sm.a.ly[3][n] = a3;
            sA00 = fmaf(a0, a0, sA00); sA01 = fmaf(a0, a1, sA01); sA11 = fmaf(a1, a1, sA11);
            mA0 += a0; mA1 += a1;
            sB00 = fmaf(a2, a2, sB00); sB01 = fmaf(a2, a3, sB01); sB11 = fmaf(a3, a3, sB11);
            mB0 += a2; mB1 += a3;
        }
#pragma unroll
        for (int off = 1; off < 64; off <<= 1) {
            sA00 += __shfl_xor(sA00, off, 64); sA01 += __shfl_xor(sA01, off, 64);
            sA11 += __shfl_xor(sA11, off, 64); mA0 += __shfl_xor(mA0, off, 64);
            mA1  += __shfl_xor(mA1,  off, 64);
            sB00 += __shfl_xor(sB00, off, 64); sB01 += __shfl_xor(sB01, off, 64);
            sB11 += __shfl_xor(sB11, off, 64); mB0 += __shfl_xor(mB0, off, 64);
            mB1  += __shfl_xor(mB1,  off, 64);
        }
        int wid = tid >> 6;
        if ((tid & 63) == 0) {
            sm.a.redg[0][wid] = sA00; sm.a.redg[1][wid] = sA01; sm.a.redg[2][wid] = sA11;
            sm.a.redg[3][wid] = mA0;  sm.a.redg[4][wid] = mA1;
            sm.a.redg[5][wid] = sB00; sm.a.redg[6][wid] = sB01; sm.a.redg[7][wid] = sB11;
            sm.a.redg[8][wid] = mB0;  sm.a.redg[9][wid] = mB1;
        }
        __syncthreads();
        sA00 = sm.a.redg[0][0] + sm.a.redg[0][1] + sm.a.redg[0][2] + sm.a.redg[0][3];
        sA01 = sm.a.redg[1][0] + sm.a.redg[1][1] + sm.a.redg[1][2] + sm.a.redg[1][3];
        sA11 = sm.a.redg[2][0] + sm.a.redg[2][1] + sm.a.redg[2][2] + sm.a.redg[2][3];
        mA0  = sm.a.redg[3][0] + sm.a.redg[3][1] + sm.a.redg[3][2] + sm.a.redg[3][3];
        mA1  = sm.a.redg[4][0] + sm.a.redg[4][1] + sm.a.redg[4][2] + sm.a.redg[4][3];
        sB00 = sm.a.redg[5][0] + sm.a.redg[5][1] + sm.a.redg[5][2] + sm.a.redg[5][3];
        sB01 = sm.a.redg[6][0] + sm.a.redg[6][1] + sm.a.redg[6][2] + sm.a.redg[6][3];
        sB11 = sm.a.redg[7][0] + sm.a.redg[7][1] + sm.a.redg[7][2] + sm.a.redg[7][3];
        mB0  = sm.a.redg[8][0] + sm.a.redg[8][1] + sm.a.redg[8][2] + sm.a.redg[8][3];
        mB1  = sm.a.redg[9][0] + sm.a.redg[9][1] + sm.a.redg[9][2] + sm.a.redg[9][3];

        float Aa, Ba, Ca, Ab, Bb, Cb;
        ca_coeffs(2 * jp,     dsel, sA00, sA01, sA11, mA0, mA1,
                  ca_wqkv, ca_bqkv, ca_t, ca_wf, ca_bf, Aa, Ba, Ca);
        ca_coeffs(2 * jp + 1, dsel, sB00, sB01, sB11, mB0, mB1,
                  ca_wqkv, ca_bqkv, ca_t, ca_wf, ca_bf, Ab, Bb, Cb);

        // ---- key moments (thread-half e2, 8 keys each) ----
        int e2 = tid >> 7, l = tid & 127;
        float wk0 = wqkv[c0 * 6 + 2 + e2], wk1 = wqkv[c1 * 6 + 2 + e2];
        float bk0 = bqkv[c0 * 6 + 2 + e2], bk1 = bqkv[c1 * 6 + 2 + e2];
        float wv0 = wqkv[c0 * 6 + 4 + e2], wv1 = wqkv[c1 * 6 + 4 + e2];
        float bv0 = bqkv[c0 * 6 + 4 + e2], bv1 = bqkv[c1 * 6 + 4 + e2];
        float mom[39];
#pragma unroll
        for (int i = 0; i < 39; ++i) mom[i] = 0.f;
#pragma unroll
        for (int kk = 0; kk < 8; ++kk) {
            int m = l + (kk << 7);
            float xa = fmaf(Aa, sm.a.ly[0][m], fmaf(Ba, sm.a.ly[1][m], Ca));
            float xb = fmaf(Ab, sm.a.ly[2][m], fmaf(Bb, sm.a.ly[3][m], Cb));
            float k0 = fmaf(wk0, xa, bk0), k1 = fmaf(wk1, xb, bk1);
            float inv = 1.f / fmaxf(sqrtf(k0 * k0 + k1 * k1), 1e-12f);
            float cp = k0 * inv, sp = k1 * inv;
            float v0 = fmaf(wv0, xa, bv0), v1 = fmaf(wv1, xb, bv1);
            mom[0] += 1.f; mom[1] += v0; mom[2] += v1;
            float c_m1 = 1.f, s_m1 = 0.f, c_r = cp, s_r = sp;
            float twoc = 2.f * cp;
#pragma unroll
            for (int r = 1; r <= NR; ++r) {
                int bi = 3 + (r - 1) * 6;
                mom[bi + 0] += c_r;
                mom[bi + 1] = fmaf(c_r, v0, mom[bi + 1]);
                mom[bi + 2] = fmaf(c_r, v1, mom[bi + 2]);
                mom[bi + 3] += s_r;
                mom[bi + 4] = fmaf(s_r, v0, mom[bi + 4]);
                mom[bi + 5] = fmaf(s_r, v1, mom[bi + 5]);
                float cn = fmaf(twoc, c_r, -c_m1);
                float sn = fmaf(twoc, s_r, -s_m1);
                c_m1 = c_r; s_m1 = s_r; c_r = cn; s_r = sn;
            }
        }
#pragma unroll
        for (int i = 0; i < 39; ++i) {
            float v = mom[i];
            v += __shfl_xor(v, 1, 64);  v += __shfl_xor(v, 2, 64);
            v += __shfl_xor(v, 4, 64);  v += __shfl_xor(v, 8, 64);
            v += __shfl_xor(v, 16, 64); v += __shfl_xor(v, 32, 64);
            mom[i] = v;
        }
        if ((tid & 63) == 0) {
#pragma unroll
            for (int i = 0; i < 39; ++i) sm.a.redm[wid][i] = mom[i];
        }
        __syncthreads();
        if (tid < 78) {
            int e = (tid >= 39) ? 1 : 0;
            int i = tid - 39 * e;
            int r = (i < 3) ? 0 : ((i - 3) / 6 + 1);
            float J[NR + 1];
            bessel_J(t[e * 32 + j], J);
            sm.a.momf[e][i] = (sm.a.redm[2 * e][i] + sm.a.redm[2 * e + 1][i]) * J[r];
        }
        __syncthreads();

        // ---- queries (1 per thread, both e) ----
        int n = (chunk << 8) + tid;
        float xan = fmaf(Aa, sm.a.ly[0][n], fmaf(Ba, sm.a.ly[1][n], Ca));
        float xbn = fmaf(Ab, sm.a.ly[2][n], fmaf(Bb, sm.a.ly[3][n], Cb));
        float oo[2][2];
#pragma unroll
        for (int e = 0; e < 2; ++e) {
            float wq0 = wqkv[c0 * 6 + e], wq1 = wqkv[c1 * 6 + e];
            float bq0 = bqkv[c0 * 6 + e], bq1 = bqkv[c1 * 6 + e];
            float q0 = fmaf(wq0, xan, bq0), q1 = fmaf(wq1, xbn, bq1);
            float qi = 1.f / fmaxf(sqrtf(q0 * q0 + q1 * q1), 1e-12f);
            float a = q0 * qi, bq = q1 * qi;
            const float* M = sm.a.momf[e];
            float den = M[0], o0 = M[1], o1 = M[2];
            float c_m1 = 1.f, s_m1 = 0.f, c_r = a, s_r = bq;
            float twoc = 2.f * a;
#pragma unroll
            for (int r = 1; r <= NR; ++r) {
                int bi = 3 + (r - 1) * 6;
                den = fmaf(c_r, M[bi + 0], den);
                o0  = fmaf(c_r, M[bi + 1], o0);
                o1  = fmaf(c_r, M[bi + 2], o1);
                den = fmaf(s_r, M[bi + 3], den);
                o0  = fmaf(s_r, M[bi + 4], o0);
                o1  = fmaf(s_r, M[bi + 5], o1);
                float cn = fmaf(twoc, c_r, -c_m1);
                float sn = fmaf(twoc, s_r, -s_m1);
                c_m1 = c_r; s_m1 = s_r; c_r = cn; s_r = sn;
            }
            float rr = 1.f / den;
            oo[e][0] = o0 * rr;
            oo[e][1] = o1 * rr;
        }
        // ---- epilogue: group fuse + un1 + pixel shuffle ----
        float t0 = fmaf(wf[c0 * 2], oo[0][0], fmaf(wf[c0 * 2 + 1], oo[1][0], bfuse[c0]));
        float t1 = fmaf(wf[c1 * 2], oo[0][1], fmaf(wf[c1 * 2 + 1], oo[1][1], bfuse[c1]));
        int i32 = n >> 5, j32 = n & 31;
        float* dst = y8 + (b * 32 + j) * 4096 + (i32 * 2) * 64 + j32 * 2;
        float z0 = fmaf(w1[(4 * j + 0) * 2], t0, fmaf(w1[(4 * j + 0) * 2 + 1], t1, b1[4 * j + 0]));
        float z1 = fmaf(w1[(4 * j + 1) * 2], t0, fmaf(w1[(4 * j + 1) * 2 + 1], t1, b1[4 * j + 1]));
        float z2 = fmaf(w1[(4 * j + 2) * 2], t0, fmaf(w1[(4 * j + 2) * 2 + 1], t1, b1[4 * j + 2]));
        float z3 = fmaf(w1[(4 * j + 3) * 2], t0, fmaf(w1[(4 * j + 3) * 2 + 1], t1, b1[4 * j + 3]));
        *(float2*)(dst)      = make_float2(z0, z1);
        *(float2*)(dst + 64) = make_float2(z2, z3);
    }
    grid_bar(bar + 1, 256);

    // ================= phase C: un2, re-tiled to 256 blocks =================
    // out[b,o,p] = sum_g w2[o,g]*y8[b,g,p] + b2[o]; block = 32 px x 64 o.
    {
        int gp0 = bid * 32;
        int b = gp0 >> 12;
        int p0 = gp0 & 4095;
        for (int idx = tid; idx < 1024; idx += 256) {
            int g = idx >> 5, pp = idx & 31;
            sm.c.lx[idx] = y8[(b * 32 + g) * 4096 + p0 + pp];
        }
        for (int idx = tid; idx < 2048; idx += 256) sm.c.lw[idx] = w2[idx];
        __syncthreads();
        int px = tid & 31, og = tid >> 5;   // og in [0,8): 8 outputs each
        float acc[8];
#pragma unroll
        for (int k = 0; k < 8; ++k) acc[k] = 0.f;
        for (int g = 0; g < 32; ++g) {
            float xv = sm.c.lx[g * 32 + px];
#pragma unroll
            for (int k = 0; k < 8; ++k)
                acc[k] = fmaf(sm.c.lw[(og * 8 + k) * 32 + g], xv, acc[k]);
        }
#pragma unroll
        for (int k = 0; k < 8; ++k) {
            int o = og * 8 + k;
            out[(b * 64 + o) * 4096 + p0 + px] = acc[k] + b2[o];
        }
    }
}

extern "C" void kernel_launch(void* const* d_in, const int* in_sizes, int n_in,
                              void* d_out, int out_size, void* d_ws, size_t ws_size,
                              hipStream_t stream) {
    (void)in_sizes; (void)n_in; (void)out_size; (void)ws_size;
    const float* x       = (const float*)d_in[0];
    const float* w_sq1   = (const float*)d_in[1];
    const float* b_sq1   = (const float*)d_in[2];
    const float* w_sq2   = (const float*)d_in[3];
    const float* b_sq2   = (const float*)d_in[4];
    const float* ca_wqkv = (const float*)d_in[5];
    const float* ca_bqkv = (const float*)d_in[6];
    const float* ca_t    = (const float*)d_in[7];
    const float* ca_wf   = (const float*)d_in[8];
    const float* ca_bf   = (const float*)d_in[9];
    const float* sa_wqkv = (const float*)d_in[10];
    const float* sa_bqkv = (const float*)d_in[11];
    const float* sa_t    = (const float*)d_in[12];
    const float* sa_wf   = (const float*)d_in[13];
    const float* sa_bf   = (const float*)d_in[14];
    const float* w_un1   = (const float*)d_in[15];
    const float* b_un1   = (const float*)d_in[16];
    const float* w_un2   = (const float*)d_in[17];
    const float* b_un2   = (const float*)d_in[18];
    float* out = (float*)d_out;
    float* ws  = (float*)d_ws;
    float* y3 = ws;                       // (2,64,1024)  = 131072 floats
    float* y8 = ws + 131072;              // (2,32,64,64) = 262144 floats
    unsigned* bar = (unsigned*)(ws + 131072 + 262144);  // 2 barrier counters

    hipMemsetAsync(bar, 0, 2 * sizeof(unsigned), stream);
    k_fused<<<256, 256, 0, stream>>>(x, w_sq1, b_sq1, w_sq2, b_sq2,
                                     ca_wqkv, ca_bqkv, ca_t, ca_wf, ca_bf,
                                     sa_wqkv, sa_bqkv, sa_t, sa_wf, sa_bf,
                                     w_un1, b_un1, w_un2, b_un2,
                                     y3, y8, out, bar);
}

// Round 2
// 125.568 us; speedup vs baseline: 1.0557x; 1.0557x over previous
//
#include <hip/hip_runtime.h>
#include <math.h>

#define NR 6   // Fourier terms r=1..NR; trunc error ~I_{NR+1}(1)/I_0(1) ~ 1.3e-6

typedef float v2f __attribute__((ext_vector_type(2)));

__device__ __forceinline__ v2f vfma2(v2f a, v2f b, v2f c) {
#if defined(__has_builtin)
#if __has_builtin(__builtin_elementwise_fma)
    return __builtin_elementwise_fma(a, b, c);
#else
    v2f r; r.x = fmaf(a.x, b.x, c.x); r.y = fmaf(a.y, b.y, c.y); return r;
#endif
#else
    v2f r; r.x = fmaf(a.x, b.x, c.x); r.y = fmaf(a.y, b.y, c.y); return r;
#endif
}

// J[r] = (r==0 ? 1 : 2) * I_r(t), modified Bessel, series (divisors fold to
// compile-time reciprocal multiplies after full unroll).
__device__ __forceinline__ void bessel_J(float t, float* J) {
    float h = 0.5f * t, q = h * h;
    float hp = 1.f, rf = 1.f;
#pragma unroll
    for (int r = 0; r <= NR; ++r) {
        if (r > 0) { hp *= h; rf *= (1.f / r); }
        float term = hp * rf, sum = term;
#pragma unroll
        for (int k = 1; k <= 12; ++k) {
            term *= q * (1.f / (k * (r + k)));
            sum += term;
        }
        J[r] = (r ? 2.f : 1.f) * sum;
    }
}

// Channel-attention collapsed map (exact): y4[2p+d] = A*y3[2p]+B*y3[2p+1]+C.
__device__ __forceinline__ void ca_coeffs(int p, int d,
        float s00, float s01, float s11, float m0, float m1,
        const float* __restrict__ wqkv, const float* __restrict__ bqkv,
        const float* __restrict__ t,    const float* __restrict__ wf,
        const float* __restrict__ bf,   float& A, float& B, float& C) {
    const float N = 1024.f;
    int c0 = 2 * p, c1 = 2 * p + 1;
    int c  = 2 * p + d;
    float Aa = 0.f, Bb = 0.f, Cc = 0.f;
#pragma unroll
    for (int e = 0; e < 2; ++e) {
        float wq0 = wqkv[c0 * 6 + e],     wq1 = wqkv[c1 * 6 + e];
        float bq0 = bqkv[c0 * 6 + e],     bq1 = bqkv[c1 * 6 + e];
        float wk0 = wqkv[c0 * 6 + 2 + e], wk1 = wqkv[c1 * 6 + 2 + e];
        float bk0 = bqkv[c0 * 6 + 2 + e], bk1 = bqkv[c1 * 6 + 2 + e];
        float wv0 = wqkv[c0 * 6 + 4 + e], wv1 = wqkv[c1 * 6 + 4 + e];
        float bv0 = bqkv[c0 * 6 + 4 + e], bv1 = bqkv[c1 * 6 + 4 + e];
        float te  = t[e * 32 + p];
        float sqq = (d == 0) ? (wq0 * wq0 * s00 + 2.f * wq0 * bq0 * m0 + N * bq0 * bq0)
                             : (wq1 * wq1 * s11 + 2.f * wq1 * bq1 * m1 + N * bq1 * bq1);
        float kk0 = wk0 * wk0 * s00 + 2.f * wk0 * bk0 * m0 + N * bk0 * bk0;
        float kk1 = wk1 * wk1 * s11 + 2.f * wk1 * bk1 * m1 + N * bk1 * bk1;
        float inq  = 1.f / fmaxf(sqrtf(fmaxf(sqq, 0.f)), 1e-12f);
        float ink0 = 1.f / fmaxf(sqrtf(fmaxf(kk0, 0.f)), 1e-12f);
        float ink1 = 1.f / fmaxf(sqrtf(fmaxf(kk1, 0.f)), 1e-12f);
        float qk0 = (d == 0) ? (wq0 * wk0 * s00 + wq0 * bk0 * m0 + bq0 * wk0 * m0 + N * bq0 * bk0)
                             : (wq1 * wk0 * s01 + wq1 * bk0 * m1 + bq1 * wk0 * m0 + N * bq1 * bk0);
        float qk1 = (d == 0) ? (wq0 * wk1 * s01 + wq0 * bk1 * m0 + bq0 * wk1 * m1 + N * bq0 * bk1)
                             : (wq1 * wk1 * s11 + wq1 * bk1 * m1 + bq1 * wk1 * m1 + N * bq1 * bk1);
        float L0 = qk0 * inq * ink0 * te, L1 = qk1 * inq * ink1 * te;
        float mx = fmaxf(L0, L1);
        float e0 = expf(L0 - mx), e1 = expf(L1 - mx);
        float iv = 1.f / (e0 + e1);
        float p0 = e0 * iv, p1 = e1 * iv;
        float f = wf[c * 2 + e];
        Aa += f * p0 * wv0;
        Bb += f * p1 * wv1;
        Cc += f * (p0 * bv0 + p1 * bv1);
    }
    A = Aa; B = Bb; C = Cc + bf[c];
}

// ---------------------------------------------------------------------------
// LDS: union of the three phase layouts (max = front, 34 KB -> worst-case
// packing still fits 4 blocks/CU, so all 256 blocks are always co-resident
// and the grid barrier cannot deadlock).
// ---------------------------------------------------------------------------
struct SmemF { float lxs[64 * 128]; float lwt[8][64]; };
struct SmemA { float ly[4][1024]; float redg[10][4]; float redm[4][39]; float momf[2][39]; };
struct SmemC { float lx[32 * 32]; float lw[64 * 32]; };
union SmemU { SmemF f; SmemA a; SmemC c; };

// ---------------------------------------------------------------------------
// Grid barrier, contention- and invalidation-aware:
//  * arrival: one RELEASE fetch_add per block into 16 counters spread 128 B
//    apart (slot = bid & 15) -> <=16 RMWs per line instead of 256 on one.
//  * spin: RELAXED loads only (no per-iteration cache invalidate), summing
//    the 16 counters, s_sleep between rounds.
//  * one ACQUIRE agent fence after exit (single buffer_inv instead of one
//    per poll iteration -- round-1's 50 us + 1.7 MB of refetch came from
//    the ACQUIRE-in-loop invalidation storm).
// Counters are zeroed by a hipMemsetAsync node before the kernel node.
// ---------------------------------------------------------------------------
#define NCTR 16
#define CSTR 32   // uints between counters = 128 B

__device__ __forceinline__ void grid_bar(unsigned* base, unsigned target) {
    __syncthreads();
    if (threadIdx.x == 0) {
        __hip_atomic_fetch_add(base + (blockIdx.x & (NCTR - 1)) * CSTR, 1u,
                               __ATOMIC_RELEASE, __HIP_MEMORY_SCOPE_AGENT);
        for (;;) {
            unsigned s = 0;
#pragma unroll
            for (int i = 0; i < NCTR; ++i)
                s += __hip_atomic_load(base + i * CSTR, __ATOMIC_RELAXED,
                                       __HIP_MEMORY_SCOPE_AGENT);
            if (s >= target) break;
            __builtin_amdgcn_s_sleep(2);
        }
        __builtin_amdgcn_fence(__ATOMIC_ACQUIRE, "agent");
    }
    __syncthreads();
}

// ---------------------------------------------------------------------------
// Single fused kernel: phase F (1x1 conv + dw 2x2/s2 + permute) ->
// grid barrier -> phase A (channel attn collapsed + spatial attn via
// Fourier/Bessel moments + fuse + un1 + shuffle) -> grid barrier ->
// phase C (un2 1x1 conv, re-tiled to 256 blocks x 32 px x 64 outputs).
// Grid: 256 blocks x 256 threads.
// ---------------------------------------------------------------------------
__global__ __launch_bounds__(256) void k_fused(
        const float* __restrict__ x,
        const float* __restrict__ w1x1, const float* __restrict__ b1x1,
        const float* __restrict__ wdw,  const float* __restrict__ bdw,
        const float* __restrict__ ca_wqkv, const float* __restrict__ ca_bqkv,
        const float* __restrict__ ca_t,    const float* __restrict__ ca_wf,
        const float* __restrict__ ca_bf,
        const float* __restrict__ wqkv, const float* __restrict__ bqkv,
        const float* __restrict__ t,    const float* __restrict__ wf,
        const float* __restrict__ bfuse, const float* __restrict__ w1,
        const float* __restrict__ b1,
        const float* __restrict__ w2,   const float* __restrict__ b2,
        float* __restrict__ y3, float* __restrict__ y8,
        float* __restrict__ out, unsigned* __restrict__ bar) {
    __shared__ __align__(16) SmemU sm;
    int tid = threadIdx.x;
    int bid = blockIdx.x;

    // ================= phase F: front (proven k_front body) =================
    {
        int q   = bid & 3;
        int i32 = (bid >> 2) & 31;
        int b   = bid >> 7;
        const float4* x4 = (const float4*)x;
#pragma unroll
        for (int i = 0; i < 8; ++i) {
            int f4 = tid + i * 256;
            int c  = f4 >> 5, cw = f4 & 31;
            ((float4*)sm.f.lxs)[f4] = x4[(b * 64 + c) * 1024 + i32 * 32 + cw];
        }
        for (int idx = tid; idx < 512; idx += 256) {
            int gi = idx >> 6, c = idx & 63;
            int g = 4 * q + (gi & 3) + ((gi & 4) << 2);
            sm.f.lwt[gi][c] = w1x1[g * 64 + c];
        }
        __syncthreads();

        int gidx = tid >> 5, col = tid & 31;
        int g = 4 * q + (gidx & 3) + ((gidx & 4) << 2);
        v2f acc0 = {0.f, 0.f}, acc1 = {0.f, 0.f};
        const v2f* lx2 = (const v2f*)sm.f.lxs;
#pragma unroll 4
        for (int c = 0; c < 64; ++c) {
            float wv = sm.f.lwt[gidx][c];
            v2f wv2 = {wv, wv};
            acc0 = vfma2(wv2, lx2[c * 64 + col], acc0);
            acc1 = vfma2(wv2, lx2[c * 64 + 32 + col], acc1);
        }
        float bs = b1x1[g];
        float a00 = acc0.x + bs, a01 = acc0.y + bs;
        float a10 = acc1.x + bs, a11 = acc1.y + bs;
#pragma unroll
        for (int s = 0; s < 2; ++s) {
            int oc = 2 * g + s;
            int k  = 2 * (oc & 31) + (oc >> 5);   // permuted y3 channel
            float4 wd = ((const float4*)wdw)[oc];
            float v = bdw[oc];
            v = fmaf(wd.x, a00, v); v = fmaf(wd.y, a01, v);
            v = fmaf(wd.z, a10, v); v = fmaf(wd.w, a11, v);
            y3[(b * 64 + k) * 1024 + i32 * 32 + col] = v;
        }
    }
    grid_bar(bar, 256);

    // ================= phase A: attention (proven k_attn body) ==============
    {
        int chunk = bid & 3;
        int j = (bid >> 2) & 31;
        int b = bid >> 7;
        int jp = j & 15;
        int dsel = j >> 4;
        int c0 = 2 * j, c1 = 2 * j + 1;

        // ---- stage 4 y3 channels + Gram stats for both ca pairs ----
        const float* base = y3 + (b * 64 + 4 * jp) * 1024;
        float sA00 = 0, sA01 = 0, sA11 = 0, mA0 = 0, mA1 = 0;
        float sB00 = 0, sB01 = 0, sB11 = 0, mB0 = 0, mB1 = 0;
#pragma unroll
        for (int r = 0; r < 4; ++r) {
            int n = tid + r * 256;
            float a0 = base[n], a1 = base[1024 + n];
            float a2 = base[2048 + n], a3 = base[3072 + n];
            sm.a.ly[0][n] = a0; sm.a.ly[1][n] = a1;
            sm.a.ly[2][n] = a2; sm.a.ly[3][n] = a3;
            sA00 = fmaf(a0, a0, sA00); sA01 = fmaf(a0, a1, sA01); sA11 = fmaf(a1, a1, sA11);
            mA0 += a0; mA1 += a1;
            sB00 = fmaf(a2, a2, sB00); sB01 = fmaf(a2, a3, sB01); sB11 = fmaf(a3, a3, sB11);
            mB0 += a2; mB1 += a3;
        }
#pragma unroll
        for (int off = 1; off < 64; off <<= 1) {
            sA00 += __shfl_xor(sA00, off, 64); sA01 += __shfl_xor(sA01, off, 64);
            sA11 += __shfl_xor(sA11, off, 64); mA0 += __shfl_xor(mA0, off, 64);
            mA1  += __shfl_xor(mA1,  off, 64);
            sB00 += __shfl_xor(sB00, off, 64); sB01 += __shfl_xor(sB01, off, 64);
            sB11 += __shfl_xor(sB11, off, 64); mB0 += __shfl_xor(mB0, off, 64);
            mB1  += __shfl_xor(mB1,  off, 64);
        }
        int wid = tid >> 6;
        if ((tid & 63) == 0) {
            sm.a.redg[0][wid] = sA00; sm.a.redg[1][wid] = sA01; sm.a.redg[2][wid] = sA11;
            sm.a.redg[3][wid] = mA0;  sm.a.redg[4][wid] = mA1;
            sm.a.redg[5][wid] = sB00; sm.a.redg[6][wid] = sB01; sm.a.redg[7][wid] = sB11;
            sm.a.redg[8][wid] = mB0;  sm.a.redg[9][wid] = mB1;
        }
        __syncthreads();
        sA00 = sm.a.redg[0][0] + sm.a.redg[0][1] + sm.a.redg[0][2] + sm.a.redg[0][3];
        sA01 = sm.a.redg[1][0] + sm.a.redg[1][1] + sm.a.redg[1][2] + sm.a.redg[1][3];
        sA11 = sm.a.redg[2][0] + sm.a.redg[2][1] + sm.a.redg[2][2] + sm.a.redg[2][3];
        mA0  = sm.a.redg[3][0] + sm.a.redg[3][1] + sm.a.redg[3][2] + sm.a.redg[3][3];
        mA1  = sm.a.redg[4][0] + sm.a.redg[4][1] + sm.a.redg[4][2] + sm.a.redg[4][3];
        sB00 = sm.a.redg[5][0] + sm.a.redg[5][1] + sm.a.redg[5][2] + sm.a.redg[5][3];
        sB01 = sm.a.redg[6][0] + sm.a.redg[6][1] + sm.a.redg[6][2] + sm.a.redg[6][3];
        sB11 = sm.a.redg[7][0] + sm.a.redg[7][1] + sm.a.redg[7][2] + sm.a.redg[7][3];
        mB0  = sm.a.redg[8][0] + sm.a.redg[8][1] + sm.a.redg[8][2] + sm.a.redg[8][3];
        mB1  = sm.a.redg[9][0] + sm.a.redg[9][1] + sm.a.redg[9][2] + sm.a.redg[9][3];

        float Aa, Ba, Ca, Ab, Bb, Cb;
        ca_coeffs(2 * jp,     dsel, sA00, sA01, sA11, mA0, mA1,
                  ca_wqkv, ca_bqkv, ca_t, ca_wf, ca_bf, Aa, Ba, Ca);
        ca_coeffs(2 * jp + 1, dsel, sB00, sB01, sB11, mB0, mB1,
                  ca_wqkv, ca_bqkv, ca_t, ca_wf, ca_bf, Ab, Bb, Cb);

        // ---- key moments (thread-half e2, 8 keys each) ----
        int e2 = tid >> 7, l = tid & 127;
        float wk0 = wqkv[c0 * 6 + 2 + e2], wk1 = wqkv[c1 * 6 + 2 + e2];
        float bk0 = bqkv[c0 * 6 + 2 + e2], bk1 = bqkv[c1 * 6 + 2 + e2];
        float wv0 = wqkv[c0 * 6 + 4 + e2], wv1 = wqkv[c1 * 6 + 4 + e2];
        float bv0 = bqkv[c0 * 6 + 4 + e2], bv1 = bqkv[c1 * 6 + 4 + e2];
        float mom[39];
#pragma unroll
        for (int i = 0; i < 39; ++i) mom[i] = 0.f;
#pragma unroll
        for (int kk = 0; kk < 8; ++kk) {
            int m = l + (kk << 7);
            float xa = fmaf(Aa, sm.a.ly[0][m], fmaf(Ba, sm.a.ly[1][m], Ca));
            float xb = fmaf(Ab, sm.a.ly[2][m], fmaf(Bb, sm.a.ly[3][m], Cb));
            float k0 = fmaf(wk0, xa, bk0), k1 = fmaf(wk1, xb, bk1);
            float inv = 1.f / fmaxf(sqrtf(k0 * k0 + k1 * k1), 1e-12f);
            float cp = k0 * inv, sp = k1 * inv;
            float v0 = fmaf(wv0, xa, bv0), v1 = fmaf(wv1, xb, bv1);
            mom[0] += 1.f; mom[1] += v0; mom[2] += v1;
            float c_m1 = 1.f, s_m1 = 0.f, c_r = cp, s_r = sp;
            float twoc = 2.f * cp;
#pragma unroll
            for (int r = 1; r <= NR; ++r) {
                int bi = 3 + (r - 1) * 6;
                mom[bi + 0] += c_r;
                mom[bi + 1] = fmaf(c_r, v0, mom[bi + 1]);
                mom[bi + 2] = fmaf(c_r, v1, mom[bi + 2]);
                mom[bi + 3] += s_r;
                mom[bi + 4] = fmaf(s_r, v0, mom[bi + 4]);
                mom[bi + 5] = fmaf(s_r, v1, mom[bi + 5]);
                float cn = fmaf(twoc, c_r, -c_m1);
                float sn = fmaf(twoc, s_r, -s_m1);
                c_m1 = c_r; s_m1 = s_r; c_r = cn; s_r = sn;
            }
        }
#pragma unroll
        for (int i = 0; i < 39; ++i) {
            float v = mom[i];
            v += __shfl_xor(v, 1, 64);  v += __shfl_xor(v, 2, 64);
            v += __shfl_xor(v, 4, 64);  v += __shfl_xor(v, 8, 64);
            v += __shfl_xor(v, 16, 64); v += __shfl_xor(v, 32, 64);
            mom[i] = v;
        }
        if ((tid & 63) == 0) {
#pragma unroll
            for (int i = 0; i < 39; ++i) sm.a.redm[wid][i] = mom[i];
        }
        __syncthreads();
        if (tid < 78) {
            int e = (tid >= 39) ? 1 : 0;
            int i = tid - 39 * e;
            int r = (i < 3) ? 0 : ((i - 3) / 6 + 1);
            float J[NR + 1];
            bessel_J(t[e * 32 + j], J);
            sm.a.momf[e][i] = (sm.a.redm[2 * e][i] + sm.a.redm[2 * e + 1][i]) * J[r];
        }
        __syncthreads();

        // ---- queries (1 per thread, both e) ----
        int n = (chunk << 8) + tid;
        float xan = fmaf(Aa, sm.a.ly[0][n], fmaf(Ba, sm.a.ly[1][n], Ca));
        float xbn = fmaf(Ab, sm.a.ly[2][n], fmaf(Bb, sm.a.ly[3][n], Cb));
        float oo[2][2];
#pragma unroll
        for (int e = 0; e < 2; ++e) {
            float wq0 = wqkv[c0 * 6 + e], wq1 = wqkv[c1 * 6 + e];
            float bq0 = bqkv[c0 * 6 + e], bq1 = bqkv[c1 * 6 + e];
            float q0 = fmaf(wq0, xan, bq0), q1 = fmaf(wq1, xbn, bq1);
            float qi = 1.f / fmaxf(sqrtf(q0 * q0 + q1 * q1), 1e-12f);
            float a = q0 * qi, bq = q1 * qi;
            const float* M = sm.a.momf[e];
            float den = M[0], o0 = M[1], o1 = M[2];
            float c_m1 = 1.f, s_m1 = 0.f, c_r = a, s_r = bq;
            float twoc = 2.f * a;
#pragma unroll
            for (int r = 1; r <= NR; ++r) {
                int bi = 3 + (r - 1) * 6;
                den = fmaf(c_r, M[bi + 0], den);
                o0  = fmaf(c_r, M[bi + 1], o0);
                o1  = fmaf(c_r, M[bi + 2], o1);
                den = fmaf(s_r, M[bi + 3], den);
                o0  = fmaf(s_r, M[bi + 4], o0);
                o1  = fmaf(s_r, M[bi + 5], o1);
                float cn = fmaf(twoc, c_r, -c_m1);
                float sn = fmaf(twoc, s_r, -s_m1);
                c_m1 = c_r; s_m1 = s_r; c_r = cn; s_r = sn;
            }
            float rr = 1.f / den;
            oo[e][0] = o0 * rr;
            oo[e][1] = o1 * rr;
        }
        // ---- epilogue: group fuse + un1 + pixel shuffle ----
        float t0 = fmaf(wf[c0 * 2], oo[0][0], fmaf(wf[c0 * 2 + 1], oo[1][0], bfuse[c0]));
        float t1 = fmaf(wf[c1 * 2], oo[0][1], fmaf(wf[c1 * 2 + 1], oo[1][1], bfuse[c1]));
        int i32 = n >> 5, j32 = n & 31;
        float* dst = y8 + (b * 32 + j) * 4096 + (i32 * 2) * 64 + j32 * 2;
        float z0 = fmaf(w1[(4 * j + 0) * 2], t0, fmaf(w1[(4 * j + 0) * 2 + 1], t1, b1[4 * j + 0]));
        float z1 = fmaf(w1[(4 * j + 1) * 2], t0, fmaf(w1[(4 * j + 1) * 2 + 1], t1, b1[4 * j + 1]));
        float z2 = fmaf(w1[(4 * j + 2) * 2], t0, fmaf(w1[(4 * j + 2) * 2 + 1], t1, b1[4 * j + 2]));
        float z3 = fmaf(w1[(4 * j + 3) * 2], t0, fmaf(w1[(4 * j + 3) * 2 + 1], t1, b1[4 * j + 3]));
        *(float2*)(dst)      = make_float2(z0, z1);
        *(float2*)(dst + 64) = make_float2(z2, z3);
    }
    grid_bar(bar + NCTR * CSTR, 256);

    // ================= phase C: un2, re-tiled to 256 blocks =================
    // out[b,o,p] = sum_g w2[o,g]*y8[b,g,p] + b2[o]; block = 32 px x 64 o.
    {
        int gp0 = bid * 32;
        int b = gp0 >> 12;
        int p0 = gp0 & 4095;
        for (int idx = tid; idx < 1024; idx += 256) {
            int g = idx >> 5, pp = idx & 31;
            sm.c.lx[idx] = y8[(b * 32 + g) * 4096 + p0 + pp];
        }
        for (int idx = tid; idx < 2048; idx += 256) sm.c.lw[idx] = w2[idx];
        __syncthreads();
        int px = tid & 31, og = tid >> 5;   // og in [0,8): 8 outputs each
        float acc[8];
#pragma unroll
        for (int k = 0; k < 8; ++k) acc[k] = 0.f;
        for (int g = 0; g < 32; ++g) {
            float xv = sm.c.lx[g * 32 + px];
#pragma unroll
            for (int k = 0; k < 8; ++k)
                acc[k] = fmaf(sm.c.lw[(og * 8 + k) * 32 + g], xv, acc[k]);
        }
#pragma unroll
        for (int k = 0; k < 8; ++k) {
            int o = og * 8 + k;
            out[(b * 64 + o) * 4096 + p0 + px] = acc[k] + b2[o];
        }
    }
}

extern "C" void kernel_launch(void* const* d_in, const int* in_sizes, int n_in,
                              void* d_out, int out_size, void* d_ws, size_t ws_size,
                              hipStream_t stream) {
    (void)in_sizes; (void)n_in; (void)out_size; (void)ws_size;
    const float* x       = (const float*)d_in[0];
    const float* w_sq1   = (const float*)d_in[1];
    const float* b_sq1   = (const float*)d_in[2];
    const float* w_sq2   = (const float*)d_in[3];
    const float* b_sq2   = (const float*)d_in[4];
    const float* ca_wqkv = (const float*)d_in[5];
    const float* ca_bqkv = (const float*)d_in[6];
    const float* ca_t    = (const float*)d_in[7];
    const float* ca_wf   = (const float*)d_in[8];
    const float* ca_bf   = (const float*)d_in[9];
    const float* sa_wqkv = (const float*)d_in[10];
    const float* sa_bqkv = (const float*)d_in[11];
    const float* sa_t    = (const float*)d_in[12];
    const float* sa_wf   = (const float*)d_in[13];
    const float* sa_bf   = (const float*)d_in[14];
    const float* w_un1   = (const float*)d_in[15];
    const float* b_un1   = (const float*)d_in[16];
    const float* w_un2   = (const float*)d_in[17];
    const float* b_un2   = (const float*)d_in[18];
    float* out = (float*)d_out;
    float* ws  = (float*)d_ws;
    float* y3 = ws;                       // (2,64,1024)  = 131072 floats
    float* y8 = ws + 131072;              // (2,32,64,64) = 262144 floats
    unsigned* bar = (unsigned*)(ws + 131072 + 262144);  // 2 x 16 counters

    hipMemsetAsync(bar, 0, 2 * NCTR * CSTR * sizeof(unsigned), stream);
    k_fused<<<256, 256, 0, stream>>>(x, w_sq1, b_sq1, w_sq2, b_sq2,
                                     ca_wqkv, ca_bqkv, ca_t, ca_wf, ca_bf,
                                     sa_wqkv, sa_bqkv, sa_t, sa_wf, sa_bf,
                                     w_un1, b_un1, w_un2, b_un2,
                                     y3, y8, out, bar);
}

// Round 3
// 109.983 us; speedup vs baseline: 1.2052x; 1.1417x over previous
//
#include <hip/hip_runtime.h>
#include <math.h>

#define NR 6   // Fourier terms r=1..NR; trunc error ~I_{NR+1}(1)/I_0(1) ~ 1.3e-6

typedef float v2f __attribute__((ext_vector_type(2)));

__device__ __forceinline__ v2f vfma2(v2f a, v2f b, v2f c) {
#if defined(__has_builtin)
#if __has_builtin(__builtin_elementwise_fma)
    return __builtin_elementwise_fma(a, b, c);
#else
    v2f r; r.x = fmaf(a.x, b.x, c.x); r.y = fmaf(a.y, b.y, c.y); return r;
#endif
#else
    v2f r; r.x = fmaf(a.x, b.x, c.x); r.y = fmaf(a.y, b.y, c.y); return r;
#endif
}

// J[r] = (r==0 ? 1 : 2) * I_r(t), modified Bessel, series (divisors fold to
// compile-time reciprocal multiplies after full unroll).
__device__ __forceinline__ void bessel_J(float t, float* J) {
    float h = 0.5f * t, q = h * h;
    float hp = 1.f, rf = 1.f;
#pragma unroll
    for (int r = 0; r <= NR; ++r) {
        if (r > 0) { hp *= h; rf *= (1.f / r); }
        float term = hp * rf, sum = term;
#pragma unroll
        for (int k = 1; k <= 12; ++k) {
            term *= q * (1.f / (k * (r + k)));
            sum += term;
        }
        J[r] = (r ? 2.f : 1.f) * sum;
    }
}

// ---------------------------------------------------------------------------
// kA: fused 1x1 conv (64->32) + depthwise 2x2/s2 conv + channel permute.
// Grid: 256 = (b:2, i32:32, q:4).  [proven R3 kernel, unchanged]
// ---------------------------------------------------------------------------
__global__ __launch_bounds__(256) void k_front(const float* __restrict__ x,
        const float* __restrict__ w1x1, const float* __restrict__ b1x1,
        const float* __restrict__ wdw,  const float* __restrict__ bdw,
        float* __restrict__ y3) {
    __shared__ float lxs[64 * 128];   // [c][col2]
    __shared__ float lwt[8][64];      // [gidx][c]
    int tid = threadIdx.x;
    int q   = blockIdx.x & 3;
    int i32 = (blockIdx.x >> 2) & 31;
    int b   = blockIdx.x >> 7;

    const float4* x4 = (const float4*)x;
#pragma unroll
    for (int i = 0; i < 8; ++i) {
        int f4 = tid + i * 256;
        int c  = f4 >> 5, cw = f4 & 31;
        ((float4*)lxs)[f4] = x4[(b * 64 + c) * 1024 + i32 * 32 + cw];
    }
    for (int idx = tid; idx < 512; idx += 256) {
        int gi = idx >> 6, c = idx & 63;
        int g = 4 * q + (gi & 3) + ((gi & 4) << 2);
        lwt[gi][c] = w1x1[g * 64 + c];
    }
    __syncthreads();

    int gidx = tid >> 5, col = tid & 31;
    int g = 4 * q + (gidx & 3) + ((gidx & 4) << 2);
    v2f acc0 = {0.f, 0.f}, acc1 = {0.f, 0.f};
    const v2f* lx2 = (const v2f*)lxs;
#pragma unroll 4
    for (int c = 0; c < 64; ++c) {
        float wv = lwt[gidx][c];
        v2f w2 = {wv, wv};
        acc0 = vfma2(w2, lx2[c * 64 + col], acc0);
        acc1 = vfma2(w2, lx2[c * 64 + 32 + col], acc1);
    }
    float bs = b1x1[g];
    float a00 = acc0.x + bs, a01 = acc0.y + bs;
    float a10 = acc1.x + bs, a11 = acc1.y + bs;
#pragma unroll
    for (int s = 0; s < 2; ++s) {
        int oc = 2 * g + s;
        int k  = 2 * (oc & 31) + (oc >> 5);   // permuted y3 channel
        float4 wd = ((const float4*)wdw)[oc];
        float v = bdw[oc];
        v = fmaf(wd.x, a00, v); v = fmaf(wd.y, a01, v);
        v = fmaf(wd.z, a10, v); v = fmaf(wd.w, a11, v);
        y3[(b * 64 + k) * 1024 + i32 * 32 + col] = v;
    }
}

// ---------------------------------------------------------------------------
// Channel-attention collapsed map (exact): y4[2p+d] = A*y3[2p]+B*y3[2p+1]+C.
// ---------------------------------------------------------------------------
__device__ __forceinline__ void ca_coeffs(int p, int d,
        float s00, float s01, float s11, float m0, float m1,
        const float* __restrict__ wqkv, const float* __restrict__ bqkv,
        const float* __restrict__ t,    const float* __restrict__ wf,
        const float* __restrict__ bf,   float& A, float& B, float& C) {
    const float N = 1024.f;
    int c0 = 2 * p, c1 = 2 * p + 1;
    int c  = 2 * p + d;
    float Aa = 0.f, Bb = 0.f, Cc = 0.f;
#pragma unroll
    for (int e = 0; e < 2; ++e) {
        float wq0 = wqkv[c0 * 6 + e],     wq1 = wqkv[c1 * 6 + e];
        float bq0 = bqkv[c0 * 6 + e],     bq1 = bqkv[c1 * 6 + e];
        float wk0 = wqkv[c0 * 6 + 2 + e], wk1 = wqkv[c1 * 6 + 2 + e];
        float bk0 = bqkv[c0 * 6 + 2 + e], bk1 = bqkv[c1 * 6 + 2 + e];
        float wv0 = wqkv[c0 * 6 + 4 + e], wv1 = wqkv[c1 * 6 + 4 + e];
        float bv0 = bqkv[c0 * 6 + 4 + e], bv1 = bqkv[c1 * 6 + 4 + e];
        float te  = t[e * 32 + p];
        float sqq = (d == 0) ? (wq0 * wq0 * s00 + 2.f * wq0 * bq0 * m0 + N * bq0 * bq0)
                             : (wq1 * wq1 * s11 + 2.f * wq1 * bq1 * m1 + N * bq1 * bq1);
        float kk0 = wk0 * wk0 * s00 + 2.f * wk0 * bk0 * m0 + N * bk0 * bk0;
        float kk1 = wk1 * wk1 * s11 + 2.f * wk1 * bk1 * m1 + N * bk1 * bk1;
        float inq  = 1.f / fmaxf(sqrtf(fmaxf(sqq, 0.f)), 1e-12f);
        float ink0 = 1.f / fmaxf(sqrtf(fmaxf(kk0, 0.f)), 1e-12f);
        float ink1 = 1.f / fmaxf(sqrtf(fmaxf(kk1, 0.f)), 1e-12f);
        float qk0 = (d == 0) ? (wq0 * wk0 * s00 + wq0 * bk0 * m0 + bq0 * wk0 * m0 + N * bq0 * bk0)
                             : (wq1 * wk0 * s01 + wq1 * bk0 * m1 + bq1 * wk0 * m0 + N * bq1 * bk0);
        float qk1 = (d == 0) ? (wq0 * wk1 * s01 + wq0 * bk1 * m0 + bq0 * wk1 * m1 + N * bq0 * bk1)
                             : (wq1 * wk1 * s11 + wq1 * bk1 * m1 + bq1 * wk1 * m1 + N * bq1 * bk1);
        float L0 = qk0 * inq * ink0 * te, L1 = qk1 * inq * ink1 * te;
        float mx = fmaxf(L0, L1);
        float e0 = expf(L0 - mx), e1 = expf(L1 - mx);
        float iv = 1.f / (e0 + e1);
        float p0 = e0 * iv, p1 = e1 * iv;
        float f = wf[c * 2 + e];
        Aa += f * p0 * wv0;
        Bb += f * p1 * wv1;
        Cc += f * (p0 * bv0 + p1 * bv1);
    }
    A = Aa; B = Bb; C = Cc + bf[c];
}

// ---------------------------------------------------------------------------
// kB: channel attention (collapsed) + nidx permute + spatial attention via
// rank-2 Fourier/Bessel moments (O(N+M)) + group fuse + un1 + pixel shuffle.
// Grid: 256 = (b:2, j:32, chunk:4); 256 threads.
// [R3 proven body; stage loop vectorized to float4 this round]
// ---------------------------------------------------------------------------
__global__ __launch_bounds__(256) void k_attn(const float* __restrict__ y3,
        const float* __restrict__ ca_wqkv, const float* __restrict__ ca_bqkv,
        const float* __restrict__ ca_t,    const float* __restrict__ ca_wf,
        const float* __restrict__ ca_bf,
        const float* __restrict__ wqkv, const float* __restrict__ bqkv,
        const float* __restrict__ t,    const float* __restrict__ wf,
        const float* __restrict__ bfuse, const float* __restrict__ w1,
        const float* __restrict__ b1,   float* __restrict__ y8) {
    __shared__ __align__(16) float ly[4][1024];
    __shared__ float redg[10][4];
    __shared__ float redm[4][39];
    __shared__ float momf[2][39];
    int tid = threadIdx.x;
    int chunk = blockIdx.x & 3;
    int j = (blockIdx.x >> 2) & 31;
    int b = blockIdx.x >> 7;
    int jp = j & 15;
    int dsel = j >> 4;
    int c0 = 2 * j, c1 = 2 * j + 1;

    // ---- phase 1: stage 4 y3 channels (float4) + Gram stats ----
    const float4* base4 = (const float4*)(y3 + (b * 64 + 4 * jp) * 1024);
    float4 a0 = base4[tid];
    float4 a1 = base4[256 + tid];
    float4 a2 = base4[512 + tid];
    float4 a3 = base4[768 + tid];
    ((float4*)ly[0])[tid] = a0; ((float4*)ly[1])[tid] = a1;
    ((float4*)ly[2])[tid] = a2; ((float4*)ly[3])[tid] = a3;
    float sA00, sA01, sA11, mA0, mA1;
    float sB00, sB01, sB11, mB0, mB1;
    sA00 = a0.x * a0.x + a0.y * a0.y + a0.z * a0.z + a0.w * a0.w;
    sA01 = a0.x * a1.x + a0.y * a1.y + a0.z * a1.z + a0.w * a1.w;
    sA11 = a1.x * a1.x + a1.y * a1.y + a1.z * a1.z + a1.w * a1.w;
    mA0  = a0.x + a0.y + a0.z + a0.w;
    mA1  = a1.x + a1.y + a1.z + a1.w;
    sB00 = a2.x * a2.x + a2.y * a2.y + a2.z * a2.z + a2.w * a2.w;
    sB01 = a2.x * a3.x + a2.y * a3.y + a2.z * a3.z + a2.w * a3.w;
    sB11 = a3.x * a3.x + a3.y * a3.y + a3.z * a3.z + a3.w * a3.w;
    mB0  = a2.x + a2.y + a2.z + a2.w;
    mB1  = a3.x + a3.y + a3.z + a3.w;
#pragma unroll
    for (int off = 1; off < 64; off <<= 1) {
        sA00 += __shfl_xor(sA00, off, 64); sA01 += __shfl_xor(sA01, off, 64);
        sA11 += __shfl_xor(sA11, off, 64); mA0 += __shfl_xor(mA0, off, 64);
        mA1  += __shfl_xor(mA1,  off, 64);
        sB00 += __shfl_xor(sB00, off, 64); sB01 += __shfl_xor(sB01, off, 64);
        sB11 += __shfl_xor(sB11, off, 64); mB0 += __shfl_xor(mB0, off, 64);
        mB1  += __shfl_xor(mB1,  off, 64);
    }
    int wid = tid >> 6;
    if ((tid & 63) == 0) {
        redg[0][wid] = sA00; redg[1][wid] = sA01; redg[2][wid] = sA11;
        redg[3][wid] = mA0;  redg[4][wid] = mA1;
        redg[5][wid] = sB00; redg[6][wid] = sB01; redg[7][wid] = sB11;
        redg[8][wid] = mB0;  redg[9][wid] = mB1;
    }
    __syncthreads();
    sA00 = redg[0][0] + redg[0][1] + redg[0][2] + redg[0][3];
    sA01 = redg[1][0] + redg[1][1] + redg[1][2] + redg[1][3];
    sA11 = redg[2][0] + redg[2][1] + redg[2][2] + redg[2][3];
    mA0  = redg[3][0] + redg[3][1] + redg[3][2] + redg[3][3];
    mA1  = redg[4][0] + redg[4][1] + redg[4][2] + redg[4][3];
    sB00 = redg[5][0] + redg[5][1] + redg[5][2] + redg[5][3];
    sB01 = redg[6][0] + redg[6][1] + redg[6][2] + redg[6][3];
    sB11 = redg[7][0] + redg[7][1] + redg[7][2] + redg[7][3];
    mB0  = redg[8][0] + redg[8][1] + redg[8][2] + redg[8][3];
    mB1  = redg[9][0] + redg[9][1] + redg[9][2] + redg[9][3];

    float Aa, Ba, Ca, Ab, Bb, Cb;
    ca_coeffs(2 * jp,     dsel, sA00, sA01, sA11, mA0, mA1,
              ca_wqkv, ca_bqkv, ca_t, ca_wf, ca_bf, Aa, Ba, Ca);
    ca_coeffs(2 * jp + 1, dsel, sB00, sB01, sB11, mB0, mB1,
              ca_wqkv, ca_bqkv, ca_t, ca_wf, ca_bf, Ab, Bb, Cb);

    // ---- phase 2: key moments (thread-half e2, 8 keys each) ----
    int e2 = tid >> 7, l = tid & 127;
    float wk0 = wqkv[c0 * 6 + 2 + e2], wk1 = wqkv[c1 * 6 + 2 + e2];
    float bk0 = bqkv[c0 * 6 + 2 + e2], bk1 = bqkv[c1 * 6 + 2 + e2];
    float wv0 = wqkv[c0 * 6 + 4 + e2], wv1 = wqkv[c1 * 6 + 4 + e2];
    float bv0 = bqkv[c0 * 6 + 4 + e2], bv1 = bqkv[c1 * 6 + 4 + e2];
    float mom[39];
#pragma unroll
    for (int i = 0; i < 39; ++i) mom[i] = 0.f;
#pragma unroll
    for (int kk = 0; kk < 8; ++kk) {
        int m = l + (kk << 7);
        float xa = fmaf(Aa, ly[0][m], fmaf(Ba, ly[1][m], Ca));
        float xb = fmaf(Ab, ly[2][m], fmaf(Bb, ly[3][m], Cb));
        float k0 = fmaf(wk0, xa, bk0), k1 = fmaf(wk1, xb, bk1);
        float inv = 1.f / fmaxf(sqrtf(k0 * k0 + k1 * k1), 1e-12f);
        float cp = k0 * inv, sp = k1 * inv;
        float v0 = fmaf(wv0, xa, bv0), v1 = fmaf(wv1, xb, bv1);
        mom[0] += 1.f; mom[1] += v0; mom[2] += v1;
        float c_m1 = 1.f, s_m1 = 0.f, c_r = cp, s_r = sp;
        float twoc = 2.f * cp;
#pragma unroll
        for (int r = 1; r <= NR; ++r) {
            int bi = 3 + (r - 1) * 6;
            mom[bi + 0] += c_r;
            mom[bi + 1] = fmaf(c_r, v0, mom[bi + 1]);
            mom[bi + 2] = fmaf(c_r, v1, mom[bi + 2]);
            mom[bi + 3] += s_r;
            mom[bi + 4] = fmaf(s_r, v0, mom[bi + 4]);
            mom[bi + 5] = fmaf(s_r, v1, mom[bi + 5]);
            float cn = fmaf(twoc, c_r, -c_m1);
            float sn = fmaf(twoc, s_r, -s_m1);
            c_m1 = c_r; s_m1 = s_r; c_r = cn; s_r = sn;
        }
    }
#pragma unroll
    for (int i = 0; i < 39; ++i) {
        float v = mom[i];
        v += __shfl_xor(v, 1, 64);  v += __shfl_xor(v, 2, 64);
        v += __shfl_xor(v, 4, 64);  v += __shfl_xor(v, 8, 64);
        v += __shfl_xor(v, 16, 64); v += __shfl_xor(v, 32, 64);
        mom[i] = v;
    }
    if ((tid & 63) == 0) {
#pragma unroll
        for (int i = 0; i < 39; ++i) redm[wid][i] = mom[i];
    }
    __syncthreads();
    if (tid < 78) {
        int e = (tid >= 39) ? 1 : 0;
        int i = tid - 39 * e;
        int r = (i < 3) ? 0 : ((i - 3) / 6 + 1);
        float J[NR + 1];
        bessel_J(t[e * 32 + j], J);
        momf[e][i] = (redm[2 * e][i] + redm[2 * e + 1][i]) * J[r];
    }
    __syncthreads();

    // ---- phase 3: queries (1 per thread, both e) ----
    int n = (chunk << 8) + tid;
    float xan = fmaf(Aa, ly[0][n], fmaf(Ba, ly[1][n], Ca));
    float xbn = fmaf(Ab, ly[2][n], fmaf(Bb, ly[3][n], Cb));
    float oo[2][2];
#pragma unroll
    for (int e = 0; e < 2; ++e) {
        float wq0 = wqkv[c0 * 6 + e], wq1 = wqkv[c1 * 6 + e];
        float bq0 = bqkv[c0 * 6 + e], bq1 = bqkv[c1 * 6 + e];
        float q0 = fmaf(wq0, xan, bq0), q1 = fmaf(wq1, xbn, bq1);
        float qi = 1.f / fmaxf(sqrtf(q0 * q0 + q1 * q1), 1e-12f);
        float a = q0 * qi, bq = q1 * qi;
        const float* M = momf[e];
        float den = M[0], o0 = M[1], o1 = M[2];
        float c_m1 = 1.f, s_m1 = 0.f, c_r = a, s_r = bq;
        float twoc = 2.f * a;
#pragma unroll
        for (int r = 1; r <= NR; ++r) {
            int bi = 3 + (r - 1) * 6;
            den = fmaf(c_r, M[bi + 0], den);
            o0  = fmaf(c_r, M[bi + 1], o0);
            o1  = fmaf(c_r, M[bi + 2], o1);
            den = fmaf(s_r, M[bi + 3], den);
            o0  = fmaf(s_r, M[bi + 4], o0);
            o1  = fmaf(s_r, M[bi + 5], o1);
            float cn = fmaf(twoc, c_r, -c_m1);
            float sn = fmaf(twoc, s_r, -s_m1);
            c_m1 = c_r; s_m1 = s_r; c_r = cn; s_r = sn;
        }
        float rr = 1.f / den;
        oo[e][0] = o0 * rr;
        oo[e][1] = o1 * rr;
    }
    // ---- epilogue: group fuse + un1 + pixel shuffle ----
    float t0 = fmaf(wf[c0 * 2], oo[0][0], fmaf(wf[c0 * 2 + 1], oo[1][0], bfuse[c0]));
    float t1 = fmaf(wf[c1 * 2], oo[0][1], fmaf(wf[c1 * 2 + 1], oo[1][1], bfuse[c1]));
    int i32 = n >> 5, j32 = n & 31;
    float* dst = y8 + (b * 32 + j) * 4096 + (i32 * 2) * 64 + j32 * 2;
    float z0 = fmaf(w1[(4 * j + 0) * 2], t0, fmaf(w1[(4 * j + 0) * 2 + 1], t1, b1[4 * j + 0]));
    float z1 = fmaf(w1[(4 * j + 1) * 2], t0, fmaf(w1[(4 * j + 1) * 2 + 1], t1, b1[4 * j + 1]));
    float z2 = fmaf(w1[(4 * j + 2) * 2], t0, fmaf(w1[(4 * j + 2) * 2 + 1], t1, b1[4 * j + 2]));
    float z3 = fmaf(w1[(4 * j + 3) * 2], t0, fmaf(w1[(4 * j + 3) * 2 + 1], t1, b1[4 * j + 3]));
    *(float2*)(dst)      = make_float2(z0, z1);
    *(float2*)(dst + 64) = make_float2(z2, z3);
}

// ---------------------------------------------------------------------------
// kC: out[b,o,p] = sum_g w_un2[o,g]*y8[b,g,p] + b_un2[o];  (2,64,4096)
// Grid: 256 blocks x 32 px, 8 outputs/thread (shape proven in fused round).
// ---------------------------------------------------------------------------
__global__ __launch_bounds__(256) void k_conv_un2(const float* __restrict__ y8,
        const float* __restrict__ w, const float* __restrict__ bias,
        float* __restrict__ out) {
    __shared__ __align__(16) float lx[32 * 32];
    __shared__ __align__(16) float lw[64 * 32];
    int tid = threadIdx.x;
    int gp0 = blockIdx.x * 32;
    int b = gp0 >> 12;
    int p0 = gp0 & 4095;
    // lx: 1024 floats = 256 float4; thread -> (g = tid>>3, f4 = tid&7)
    {
        int g = tid >> 3, f4 = tid & 7;
        ((float4*)lx)[tid] =
            ((const float4*)y8)[(b * 32 + g) * 1024 + (p0 >> 2) + f4];
    }
    // lw: 2048 floats = 512 float4
    {
        ((float4*)lw)[tid]       = ((const float4*)w)[tid];
        ((float4*)lw)[256 + tid] = ((const float4*)w)[256 + tid];
    }
    __syncthreads();
    int px = tid & 31, og = tid >> 5;   // og in [0,8): 8 outputs each
    float acc[8];
#pragma unroll
    for (int k = 0; k < 8; ++k) acc[k] = 0.f;
    for (int g = 0; g < 32; ++g) {
        float xv = lx[g * 32 + px];
#pragma unroll
        for (int k = 0; k < 8; ++k)
            acc[k] = fmaf(lw[(og * 8 + k) * 32 + g], xv, acc[k]);
    }
#pragma unroll
    for (int k = 0; k < 8; ++k) {
        int o = og * 8 + k;
        out[(b * 64 + o) * 4096 + p0 + px] = acc[k] + bias[o];
    }
}

extern "C" void kernel_launch(void* const* d_in, const int* in_sizes, int n_in,
                              void* d_out, int out_size, void* d_ws, size_t ws_size,
                              hipStream_t stream) {
    (void)in_sizes; (void)n_in; (void)out_size; (void)ws_size;
    const float* x       = (const float*)d_in[0];
    const float* w_sq1   = (const float*)d_in[1];
    const float* b_sq1   = (const float*)d_in[2];
    const float* w_sq2   = (const float*)d_in[3];
    const float* b_sq2   = (const float*)d_in[4];
    const float* ca_wqkv = (const float*)d_in[5];
    const float* ca_bqkv = (const float*)d_in[6];
    const float* ca_t    = (const float*)d_in[7];
    const float* ca_wf   = (const float*)d_in[8];
    const float* ca_bf   = (const float*)d_in[9];
    const float* sa_wqkv = (const float*)d_in[10];
    const float* sa_bqkv = (const float*)d_in[11];
    const float* sa_t    = (const float*)d_in[12];
    const float* sa_wf   = (const float*)d_in[13];
    const float* sa_bf   = (const float*)d_in[14];
    const float* w_un1   = (const float*)d_in[15];
    const float* b_un1   = (const float*)d_in[16];
    const float* w_un2   = (const float*)d_in[17];
    const float* b_un2   = (const float*)d_in[18];
    float* out = (float*)d_out;
    float* ws  = (float*)d_ws;
    float* y3 = ws;                 // (2,64,1024)  = 131072 floats
    float* y8 = ws + 131072;        // (2,32,64,64) = 262144 floats

    k_front<<<256, 256, 0, stream>>>(x, w_sq1, b_sq1, w_sq2, b_sq2, y3);
    k_attn <<<256, 256, 0, stream>>>(y3, ca_wqkv, ca_bqkv, ca_t, ca_wf, ca_bf,
                                     sa_wqkv, sa_bqkv, sa_t, sa_wf, sa_bf,
                                     w_un1, b_un1, y8);
    k_conv_un2<<<256, 256, 0, stream>>>(y8, w_un2, b_un2, out);
}